// Round 1
// baseline (1066.920 us; speedup 1.0000x reference)
//
#include <hip/hip_runtime.h>
#include <hip/hip_bf16.h>

// ---------------------------------------------------------------------------
// Decoder block for B=4, T=2048, E=1024, H=16, HD=64, V=32000.
// bf16 MFMA compute, f32 residual/LN master copies.
// ---------------------------------------------------------------------------

typedef __attribute__((ext_vector_type(8))) short v8s;   // 8 bf16 (4 VGPR) MFMA operand
typedef __attribute__((ext_vector_type(4))) float v4f;   // MFMA accumulator

#define MFMA16(a, b, c) __builtin_amdgcn_mfma_f32_16x16x32_bf16((a), (b), (c), 0, 0, 0)

typedef const __attribute__((address_space(1))) void* gas1_t;
typedef __attribute__((address_space(3))) void* las3_t;

__device__ __forceinline__ void gl_lds16(const void* g, void* l) {
  // async global->LDS, 16B per lane; LDS dest must be wave-uniform (HW adds lane*16B)
  __builtin_amdgcn_global_load_lds((gas1_t)g, (las3_t)l, 16, 0, 0);
}

__device__ __forceinline__ unsigned short f2bf(float f) {
  __hip_bfloat16 h = __float2bfloat16(f);
  return *reinterpret_cast<unsigned short*>(&h);
}

// ---------------------------------------------------------------------------
// Weight prep: src[K][N] f32 -> dst[N][K] bf16 (transpose + convert)
// ---------------------------------------------------------------------------
__global__ __launch_bounds__(256)
void transpose_bf16(const float* __restrict__ src, unsigned short* __restrict__ dst,
                    int K, int N) {
  __shared__ float tile[32][33];
  const int n0 = blockIdx.x * 32, k0 = blockIdx.y * 32;
  const int tx = threadIdx.x & 31, ty = threadIdx.x >> 5;  // 32 x 8
#pragma unroll
  for (int i = 0; i < 32; i += 8)
    tile[ty + i][tx] = src[(size_t)(k0 + ty + i) * N + n0 + tx];
  __syncthreads();
#pragma unroll
  for (int i = 0; i < 32; i += 8)
    dst[(size_t)(n0 + ty + i) * K + k0 + tx] = f2bf(tile[tx][ty + i]);
}

// ---------------------------------------------------------------------------
// Embedding: resid = tok_emb[x] + pos_emb, plus bf16 copy
// ---------------------------------------------------------------------------
__global__ __launch_bounds__(256)
void embed_k(const int* __restrict__ x, const float* __restrict__ tok,
             const float* __restrict__ pos, float* __restrict__ resid,
             unsigned short* __restrict__ act) {
  const int t = blockIdx.x, tid = threadIdx.x;
  const int id = x[t], tp = t & 2047;
  float4 v = ((const float4*)(tok + (size_t)id * 1024))[tid];
  float4 p = ((const float4*)(pos + (size_t)tp * 1024))[tid];
  v.x += p.x; v.y += p.y; v.z += p.z; v.w += p.w;
  ((float4*)(resid + (size_t)t * 1024))[tid] = v;
  ushort4 u;
  u.x = f2bf(v.x); u.y = f2bf(v.y); u.z = f2bf(v.z); u.w = f2bf(v.w);
  ((ushort4*)(act + (size_t)t * 1024))[tid] = u;
}

// ---------------------------------------------------------------------------
// GEMM: C[M][N] = A[M][K](bf16) @ Bt[N][K]^T(bf16)  (+bias) (+relu)
// flags: bit0 = relu, bit1 = bf16 output (else f32)
// 128x128 tile, BK=64, 4 waves (2x2), each wave 64x64 via 4x4 16x16x32 MFMA.
// ---------------------------------------------------------------------------
__global__ __launch_bounds__(256)
void gemm_bt(const unsigned short* __restrict__ A, const unsigned short* __restrict__ Bt,
             const float* __restrict__ bias, void* __restrict__ C,
             int M, int N, int K, int flags) {
  __shared__ __align__(16) unsigned short As[128 * 64];
  __shared__ __align__(16) unsigned short Bs[128 * 64];
  const int tid = threadIdx.x;
  const int w = tid >> 6, l = tid & 63;
  const int lr = l & 15, lg = l >> 4;
  const int wm = w & 1, wn = w >> 1;
  const int m0 = blockIdx.x * 128, n0 = blockIdx.y * 128;
  const int ra = l >> 3, ka = (l & 7) * 8;   // staging: row-in-chunk, k offset

  v4f acc[4][4];
  const v4f vzero = {0.f, 0.f, 0.f, 0.f};
#pragma unroll
  for (int m = 0; m < 4; ++m)
#pragma unroll
    for (int n = 0; n < 4; ++n) acc[m][n] = vzero;

  for (int k0 = 0; k0 < K; k0 += 64) {
    // stage A,B tiles: 16 chunks of 1KB each (8 rows x 64 k), wave w takes c=w,w+4,w+8,w+12
#pragma unroll
    for (int i = 0; i < 4; ++i) {
      const int c = w + i * 4;
      gl_lds16(A  + (size_t)(m0 + c * 8 + ra) * K + k0 + ka, &As[c * 512]);
      gl_lds16(Bt + (size_t)(n0 + c * 8 + ra) * K + k0 + ka, &Bs[c * 512]);
    }
    __syncthreads();
#pragma unroll
    for (int kk = 0; kk < 2; ++kk) {
      v8s af[4], bb[4];
#pragma unroll
      for (int m = 0; m < 4; ++m)
        af[m] = *(const v8s*)&As[(wm * 64 + m * 16 + lr) * 64 + kk * 32 + lg * 8];
#pragma unroll
      for (int n = 0; n < 4; ++n)
        bb[n] = *(const v8s*)&Bs[(wn * 64 + n * 16 + lr) * 64 + kk * 32 + lg * 8];
#pragma unroll
      for (int m = 0; m < 4; ++m)
#pragma unroll
        for (int n = 0; n < 4; ++n)
          acc[m][n] = MFMA16(af[m], bb[n], acc[m][n]);
    }
    __syncthreads();
  }

  const bool relu = flags & 1, obf = flags & 2;
#pragma unroll
  for (int n = 0; n < 4; ++n) {
    const int col = n0 + wn * 64 + n * 16 + lr;
    const float bv = bias ? bias[col] : 0.f;
#pragma unroll
    for (int m = 0; m < 4; ++m) {
      const int row = m0 + wm * 64 + m * 16 + lg * 4;
#pragma unroll
      for (int r = 0; r < 4; ++r) {
        float v = acc[m][n][r] + bv;
        if (relu) v = fmaxf(v, 0.f);
        if (obf) ((unsigned short*)C)[(size_t)(row + r) * N + col] = f2bf(v);
        else     ((float*)C)[(size_t)(row + r) * N + col] = v;
      }
    }
  }
}

// ---------------------------------------------------------------------------
// Flash attention: Q,K,V,O are [8192][1024] bf16, head slice = cols h*64..+63.
// Block = 64 q rows (4 waves x 16), KV tiles of 64. Online softmax.
// C/D layout: row=(l>>4)*4+reg, col=l&15 (verified m89).
// ---------------------------------------------------------------------------
template <bool CAUSAL>
__global__ __launch_bounds__(256)
void flash_attn(const unsigned short* __restrict__ Q, const unsigned short* __restrict__ Kg,
                const unsigned short* __restrict__ Vg, unsigned short* __restrict__ O) {
  __shared__ __align__(16) unsigned short Kt[64 * 64];      // [kv][d]
  __shared__ __align__(16) unsigned short Vt[64 * 64];      // [d][kv] (transposed)
  __shared__ __align__(16) unsigned short Pl[4 * 16 * 64];  // per-wave P tile [16][64]
  const int tid = threadIdx.x;
  const int w = tid >> 6, l = tid & 63, lr = l & 15, lg = l >> 4;
  const int b = blockIdx.y >> 4, h = blockIdx.y & 15;
  const int q0 = blockIdx.x * 64 + w * 16;                  // batch-local q base of this wave
  const size_t base = ((size_t)b * 2048) * 1024 + h * 64;

  // Q fragments (A operand), held for the whole kv loop
  const unsigned short* qp = Q + base + (size_t)(q0 + lr) * 1024 + lg * 8;
  const v8s qf0 = *(const v8s*)qp;
  const v8s qf1 = *(const v8s*)(qp + 32);

  v4f acc[4];
  const v4f vzero = {0.f, 0.f, 0.f, 0.f};
#pragma unroll
  for (int n = 0; n < 4; ++n) acc[n] = vzero;
  float mrow[4] = {-INFINITY, -INFINITY, -INFINITY, -INFINITY};
  float lrow[4] = {0.f, 0.f, 0.f, 0.f};

  const int kv_end = CAUSAL ? (blockIdx.x * 64 + 64) : 2048;
  const int vr = tid >> 2, vd = (tid & 3) * 16;  // V-transpose staging assignment

  for (int kv0 = 0; kv0 < kv_end; kv0 += 64) {
    // stage K tile (linear, via async global->LDS): 8 chunks of 1KB
#pragma unroll
    for (int i = 0; i < 2; ++i) {
      const int c = w + i * 4;
      gl_lds16(Kg + base + (size_t)(kv0 + c * 8 + (l >> 3)) * 1024 + (l & 7) * 8,
               &Kt[c * 512]);
    }
    // stage V transposed: each thread 1 row-quarter (16 d) -> 16 scattered ds_write
    {
      const unsigned short* vp = Vg + base + (size_t)(kv0 + vr) * 1024 + vd;
      const v8s v0 = *(const v8s*)vp;
      const v8s v1 = *(const v8s*)(vp + 8);
#pragma unroll
      for (int j = 0; j < 8; ++j) {
        Vt[(vd + j) * 64 + vr]     = (unsigned short)v0[j];
        Vt[(vd + 8 + j) * 64 + vr] = (unsigned short)v1[j];
      }
    }
    __syncthreads();

    // S = (Q K^T) * 1/sqrt(64)
    v4f s[4];
#pragma unroll
    for (int n = 0; n < 4; ++n) s[n] = vzero;
#pragma unroll
    for (int kk = 0; kk < 2; ++kk) {
#pragma unroll
      for (int n = 0; n < 4; ++n) {
        const v8s kf = *(const v8s*)&Kt[(n * 16 + lr) * 64 + kk * 32 + lg * 8];
        s[n] = MFMA16(kk ? qf1 : qf0, kf, s[n]);
      }
    }
#pragma unroll
    for (int n = 0; n < 4; ++n)
#pragma unroll
      for (int r = 0; r < 4; ++r) s[n][r] *= 0.125f;

    if (CAUSAL && (kv0 + 63 > q0)) {
#pragma unroll
      for (int n = 0; n < 4; ++n) {
        const int kc = kv0 + n * 16 + lr;
#pragma unroll
        for (int r = 0; r < 4; ++r)
          if (kc > q0 + lg * 4 + r) s[n][r] = -INFINITY;
      }
    }

    // online softmax (rows live in regs: row = lg*4 + r; reduce over 16 lanes)
    float tm[4], fac[4], rs[4];
#pragma unroll
    for (int r = 0; r < 4; ++r)
      tm[r] = fmaxf(fmaxf(s[0][r], s[1][r]), fmaxf(s[2][r], s[3][r]));
#pragma unroll
    for (int off = 1; off < 16; off <<= 1)
#pragma unroll
      for (int r = 0; r < 4; ++r) tm[r] = fmaxf(tm[r], __shfl_xor(tm[r], off));
#pragma unroll
    for (int r = 0; r < 4; ++r) {
      const float mn = fmaxf(mrow[r], tm[r]);
      fac[r] = __expf(mrow[r] - mn);
      mrow[r] = mn;
    }
#pragma unroll
    for (int n = 0; n < 4; ++n)
#pragma unroll
      for (int r = 0; r < 4; ++r) s[n][r] = __expf(s[n][r] - mrow[r]);
#pragma unroll
    for (int r = 0; r < 4; ++r) rs[r] = s[0][r] + s[1][r] + s[2][r] + s[3][r];
#pragma unroll
    for (int off = 1; off < 16; off <<= 1)
#pragma unroll
      for (int r = 0; r < 4; ++r) rs[r] += __shfl_xor(rs[r], off);
#pragma unroll
    for (int r = 0; r < 4; ++r) lrow[r] = lrow[r] * fac[r] + rs[r];
#pragma unroll
    for (int n = 0; n < 4; ++n)
#pragma unroll
      for (int r = 0; r < 4; ++r) acc[n][r] *= fac[r];

    // P -> per-wave LDS (re-layout C-frag -> A-frag), then PV
    unsigned short* Pw = &Pl[w * 1024];
#pragma unroll
    for (int n = 0; n < 4; ++n)
#pragma unroll
      for (int r = 0; r < 4; ++r)
        Pw[(lg * 4 + r) * 64 + n * 16 + lr] = f2bf(s[n][r]);
#pragma unroll
    for (int kk = 0; kk < 2; ++kk) {
      const v8s pf = *(const v8s*)&Pw[lr * 64 + kk * 32 + lg * 8];
#pragma unroll
      for (int n = 0; n < 4; ++n) {
        const v8s vf = *(const v8s*)&Vt[(n * 16 + lr) * 64 + kk * 32 + lg * 8];
        acc[n] = MFMA16(pf, vf, acc[n]);
      }
    }
    __syncthreads();
  }

  // epilogue: O = acc / l
#pragma unroll
  for (int n = 0; n < 4; ++n)
#pragma unroll
    for (int r = 0; r < 4; ++r) {
      const float v = acc[n][r] / lrow[r];
      O[base + (size_t)(q0 + lg * 4 + r) * 1024 + n * 16 + lr] = f2bf(v);
    }
}

// ---------------------------------------------------------------------------
// Fused residual-add + LayerNorm (one block per token row of 1024)
// ---------------------------------------------------------------------------
__global__ __launch_bounds__(256)
void add_ln(const float* __restrict__ ra, const float* __restrict__ rb,
            const float* __restrict__ g, const float* __restrict__ be,
            float* __restrict__ of, unsigned short* __restrict__ act) {
  const int t = blockIdx.x, tid = threadIdx.x;
  const float4 va = ((const float4*)(ra + (size_t)t * 1024))[tid];
  const float4 vb = ((const float4*)(rb + (size_t)t * 1024))[tid];
  float4 s;
  s.x = va.x + vb.x; s.y = va.y + vb.y; s.z = va.z + vb.z; s.w = va.w + vb.w;
  float sum = s.x + s.y + s.z + s.w;
  float sq  = s.x * s.x + s.y * s.y + s.z * s.z + s.w * s.w;
#pragma unroll
  for (int off = 32; off > 0; off >>= 1) {
    sum += __shfl_xor(sum, off);
    sq  += __shfl_xor(sq, off);
  }
  __shared__ float red[8];
  const int w = tid >> 6;
  if ((tid & 63) == 0) { red[w] = sum; red[4 + w] = sq; }
  __syncthreads();
  sum = red[0] + red[1] + red[2] + red[3];
  sq  = red[4] + red[5] + red[6] + red[7];
  const float mean = sum * (1.f / 1024.f);
  const float var  = sq * (1.f / 1024.f) - mean * mean;
  const float rstd = rsqrtf(var + 1e-5f);
  const float4 gg = ((const float4*)g)[tid];
  const float4 bb = ((const float4*)be)[tid];
  float4 y;
  y.x = (s.x - mean) * rstd * gg.x + bb.x;
  y.y = (s.y - mean) * rstd * gg.y + bb.y;
  y.z = (s.z - mean) * rstd * gg.z + bb.z;
  y.w = (s.w - mean) * rstd * gg.w + bb.w;
  ((float4*)(of + (size_t)t * 1024))[tid] = y;
  if (act) {
    ushort4 u;
    u.x = f2bf(y.x); u.y = f2bf(y.y); u.z = f2bf(y.z); u.w = f2bf(y.w);
    ((ushort4*)(act + (size_t)t * 1024))[tid] = u;
  }
}

// ---------------------------------------------------------------------------
extern "C" void kernel_launch(void* const* d_in, const int* in_sizes, int n_in,
                              void* d_out, int out_size, void* d_ws, size_t ws_size,
                              hipStream_t stream) {
  const int*   x    = (const int*)d_in[0];
  const float* tok  = (const float*)d_in[1];
  const float* pos  = (const float*)d_in[2];
  const float* mWq  = (const float*)d_in[3];
  const float* mWk  = (const float*)d_in[4];
  const float* mWv  = (const float*)d_in[5];
  const float* mWo  = (const float*)d_in[6];
  const float* m_bo = (const float*)d_in[7];
  const float* hWq  = (const float*)d_in[8];
  const float* hWk  = (const float*)d_in[9];
  const float* hWv  = (const float*)d_in[10];
  const float* hWo  = (const float*)d_in[11];
  const float* h_bo = (const float*)d_in[12];
  const float* fW1  = (const float*)d_in[13];
  const float* f_b1 = (const float*)d_in[14];
  const float* fW2  = (const float*)d_in[15];
  const float* f_b2 = (const float*)d_in[16];
  const float* fW3  = (const float*)d_in[17];
  const float* f_b3 = (const float*)d_in[18];
  const float* fW4  = (const float*)d_in[19];
  const float* f_b4 = (const float*)d_in[20];
  const float* ln_g = (const float*)d_in[21];
  const float* ln_b = (const float*)d_in[22];

  char* ws = (char*)d_ws;
  const size_t MB = 1ull << 20;
  unsigned short* mWq_t = (unsigned short*)(ws + 0 * MB);
  unsigned short* mWk_t = (unsigned short*)(ws + 2 * MB);
  unsigned short* mWv_t = (unsigned short*)(ws + 4 * MB);
  unsigned short* mWo_t = (unsigned short*)(ws + 6 * MB);
  unsigned short* hWq_t = (unsigned short*)(ws + 8 * MB);
  unsigned short* hWk_t = (unsigned short*)(ws + 10 * MB);
  unsigned short* hWv_t = (unsigned short*)(ws + 12 * MB);
  unsigned short* hWo_t = (unsigned short*)(ws + 14 * MB);
  unsigned short* fW1_t = (unsigned short*)(ws + 16 * MB);
  unsigned short* fW2_t = (unsigned short*)(ws + 17 * MB);
  unsigned short* fW3_t = (unsigned short*)(ws + 18 * MB);
  unsigned short* fW4_t = (unsigned short*)(ws + 19 * MB);
  float*          resid = (float*)(ws + 20 * MB);           // 32 MB
  float*          tmp   = (float*)(ws + 52 * MB);           // 32 MB
  unsigned short* act   = (unsigned short*)(ws + 84 * MB);  // 16 MB
  unsigned short* qb    = (unsigned short*)(ws + 100 * MB); // 16 MB (also FFN h1)
  unsigned short* kb    = (unsigned short*)(ws + 116 * MB); // 16 MB (also FFN h2)
  unsigned short* vb    = (unsigned short*)(ws + 132 * MB); // 16 MB (also FFN h3)
  unsigned short* attno = (unsigned short*)(ws + 148 * MB); // 16 MB

  // ---- weight prep: f32 [K][N] -> bf16 [N][K]
  transpose_bf16<<<dim3(32, 32), 256, 0, stream>>>(mWq, mWq_t, 1024, 1024);
  transpose_bf16<<<dim3(32, 32), 256, 0, stream>>>(mWk, mWk_t, 1024, 1024);
  transpose_bf16<<<dim3(32, 32), 256, 0, stream>>>(mWv, mWv_t, 1024, 1024);
  transpose_bf16<<<dim3(32, 32), 256, 0, stream>>>(mWo, mWo_t, 1024, 1024);
  transpose_bf16<<<dim3(32, 32), 256, 0, stream>>>(hWq, hWq_t, 1024, 1024);
  transpose_bf16<<<dim3(32, 32), 256, 0, stream>>>(hWk, hWk_t, 1024, 1024);
  transpose_bf16<<<dim3(32, 32), 256, 0, stream>>>(hWv, hWv_t, 1024, 1024);
  transpose_bf16<<<dim3(32, 32), 256, 0, stream>>>(hWo, hWo_t, 1024, 1024);
  transpose_bf16<<<dim3(16, 32), 256, 0, stream>>>(fW1, fW1_t, 1024, 512);
  transpose_bf16<<<dim3(32, 16), 256, 0, stream>>>(fW2, fW2_t, 512, 1024);
  transpose_bf16<<<dim3(16, 32), 256, 0, stream>>>(fW3, fW3_t, 1024, 512);
  transpose_bf16<<<dim3(32, 16), 256, 0, stream>>>(fW4, fW4_t, 512, 1024);

  // ---- embedding
  embed_k<<<8192, 256, 0, stream>>>(x, tok, pos, resid, act);

  // ---- block 1: causal MHA
  gemm_bt<<<dim3(64, 8), 256, 0, stream>>>(act, mWq_t, nullptr, qb, 8192, 1024, 1024, 2);
  gemm_bt<<<dim3(64, 8), 256, 0, stream>>>(act, mWk_t, nullptr, kb, 8192, 1024, 1024, 2);
  gemm_bt<<<dim3(64, 8), 256, 0, stream>>>(act, mWv_t, nullptr, vb, 8192, 1024, 1024, 2);
  flash_attn<true><<<dim3(32, 64), 256, 0, stream>>>(qb, kb, vb, attno);
  gemm_bt<<<dim3(64, 8), 256, 0, stream>>>(attno, mWo_t, m_bo, tmp, 8192, 1024, 1024, 0);
  add_ln<<<8192, 256, 0, stream>>>(resid, tmp, ln_g, ln_b, resid, act);

  // ---- block 2: full (non-causal) MHA
  gemm_bt<<<dim3(64, 8), 256, 0, stream>>>(act, hWq_t, nullptr, qb, 8192, 1024, 1024, 2);
  gemm_bt<<<dim3(64, 8), 256, 0, stream>>>(act, hWk_t, nullptr, kb, 8192, 1024, 1024, 2);
  gemm_bt<<<dim3(64, 8), 256, 0, stream>>>(act, hWv_t, nullptr, vb, 8192, 1024, 1024, 2);
  flash_attn<false><<<dim3(32, 64), 256, 0, stream>>>(qb, kb, vb, attno);
  gemm_bt<<<dim3(64, 8), 256, 0, stream>>>(attno, hWo_t, h_bo, tmp, 8192, 1024, 1024, 0);
  add_ln<<<8192, 256, 0, stream>>>(resid, tmp, ln_g, ln_b, resid, act);

  // ---- FFN
  gemm_bt<<<dim3(64, 4), 256, 0, stream>>>(act, fW1_t, f_b1, qb, 8192, 512, 1024, 3);
  gemm_bt<<<dim3(64, 8), 256, 0, stream>>>(qb,  fW2_t, f_b2, kb, 8192, 1024, 512, 3);
  gemm_bt<<<dim3(64, 4), 256, 0, stream>>>(kb,  fW3_t, f_b3, vb, 8192, 512, 1024, 3);
  gemm_bt<<<dim3(64, 8), 256, 0, stream>>>(vb,  fW4_t, f_b4, tmp, 8192, 1024, 512, 0);
  add_ln<<<8192, 256, 0, stream>>>(resid, tmp, ln_g, ln_b, (float*)d_out, nullptr);
}

// Round 2
// 851.206 us; speedup vs baseline: 1.2534x; 1.2534x over previous
//
#include <hip/hip_runtime.h>
#include <hip/hip_bf16.h>

// ---------------------------------------------------------------------------
// Decoder block for B=4, T=2048, E=1024, H=16, HD=64, V=32000.
// bf16 MFMA compute, f32 residual/LN master copies.
// R2: flash_attn LDS XOR-swizzle (K/V/P), conflict-free V staging,
//     exp2-domain softmax w/ pre-scaled Q, defer-max, setprio.
// ---------------------------------------------------------------------------

typedef __attribute__((ext_vector_type(8))) short v8s;   // 8 bf16 (4 VGPR) MFMA operand
typedef __attribute__((ext_vector_type(4))) float v4f;   // MFMA accumulator

#define MFMA16(a, b, c) __builtin_amdgcn_mfma_f32_16x16x32_bf16((a), (b), (c), 0, 0, 0)

typedef const __attribute__((address_space(1))) void* gas1_t;
typedef __attribute__((address_space(3))) void* las3_t;

__device__ __forceinline__ void gl_lds16(const void* g, void* l) {
  // async global->LDS, 16B per lane; LDS dest must be wave-uniform (HW adds lane*16B)
  __builtin_amdgcn_global_load_lds((gas1_t)g, (las3_t)l, 16, 0, 0);
}

__device__ __forceinline__ unsigned short f2bf(float f) {
  __hip_bfloat16 h = __float2bfloat16(f);
  return *reinterpret_cast<unsigned short*>(&h);
}

__device__ __forceinline__ float fast_exp2(float x) {
  float r;
  asm("v_exp_f32 %0, %1" : "=v"(r) : "v"(x));  // D = 2^S0, -inf -> 0
  return r;
}

// log2(e)/sqrt(HD) folded into the Q projection
#define QSCALE 0.18033688011112042f

// ---------------------------------------------------------------------------
// Weight prep: src[K][N] f32 -> dst[N][K] bf16 (transpose + convert)
// ---------------------------------------------------------------------------
__global__ __launch_bounds__(256)
void transpose_bf16(const float* __restrict__ src, unsigned short* __restrict__ dst,
                    int K, int N) {
  __shared__ float tile[32][33];
  const int n0 = blockIdx.x * 32, k0 = blockIdx.y * 32;
  const int tx = threadIdx.x & 31, ty = threadIdx.x >> 5;  // 32 x 8
#pragma unroll
  for (int i = 0; i < 32; i += 8)
    tile[ty + i][tx] = src[(size_t)(k0 + ty + i) * N + n0 + tx];
  __syncthreads();
#pragma unroll
  for (int i = 0; i < 32; i += 8)
    dst[(size_t)(n0 + ty + i) * K + k0 + tx] = f2bf(tile[tx][ty + i]);
}

// ---------------------------------------------------------------------------
// Embedding: resid = tok_emb[x] + pos_emb, plus bf16 copy
// ---------------------------------------------------------------------------
__global__ __launch_bounds__(256)
void embed_k(const int* __restrict__ x, const float* __restrict__ tok,
             const float* __restrict__ pos, float* __restrict__ resid,
             unsigned short* __restrict__ act) {
  const int t = blockIdx.x, tid = threadIdx.x;
  const int id = x[t], tp = t & 2047;
  float4 v = ((const float4*)(tok + (size_t)id * 1024))[tid];
  float4 p = ((const float4*)(pos + (size_t)tp * 1024))[tid];
  v.x += p.x; v.y += p.y; v.z += p.z; v.w += p.w;
  ((float4*)(resid + (size_t)t * 1024))[tid] = v;
  ushort4 u;
  u.x = f2bf(v.x); u.y = f2bf(v.y); u.z = f2bf(v.z); u.w = f2bf(v.w);
  ((ushort4*)(act + (size_t)t * 1024))[tid] = u;
}

// ---------------------------------------------------------------------------
// GEMM: C[M][N] = A[M][K](bf16) @ Bt[N][K]^T(bf16)  (+bias) (+relu)
// flags: bit0 = relu, bit1 = bf16 output (else f32), bit2 = scale by QSCALE
// 128x128 tile, BK=64, 4 waves (2x2), each wave 64x64 via 4x4 16x16x32 MFMA.
// ---------------------------------------------------------------------------
__global__ __launch_bounds__(256)
void gemm_bt(const unsigned short* __restrict__ A, const unsigned short* __restrict__ Bt,
             const float* __restrict__ bias, void* __restrict__ C,
             int M, int N, int K, int flags) {
  __shared__ __align__(16) unsigned short As[128 * 64];
  __shared__ __align__(16) unsigned short Bs[128 * 64];
  const int tid = threadIdx.x;
  const int w = tid >> 6, l = tid & 63;
  const int lr = l & 15, lg = l >> 4;
  const int wm = w & 1, wn = w >> 1;
  const int m0 = blockIdx.x * 128, n0 = blockIdx.y * 128;
  const int ra = l >> 3, ka = (l & 7) * 8;   // staging: row-in-chunk, k offset

  v4f acc[4][4];
  const v4f vzero = {0.f, 0.f, 0.f, 0.f};
#pragma unroll
  for (int m = 0; m < 4; ++m)
#pragma unroll
    for (int n = 0; n < 4; ++n) acc[m][n] = vzero;

  for (int k0 = 0; k0 < K; k0 += 64) {
#pragma unroll
    for (int i = 0; i < 4; ++i) {
      const int c = w + i * 4;
      gl_lds16(A  + (size_t)(m0 + c * 8 + ra) * K + k0 + ka, &As[c * 512]);
      gl_lds16(Bt + (size_t)(n0 + c * 8 + ra) * K + k0 + ka, &Bs[c * 512]);
    }
    __syncthreads();
#pragma unroll
    for (int kk = 0; kk < 2; ++kk) {
      v8s af[4], bb[4];
#pragma unroll
      for (int m = 0; m < 4; ++m)
        af[m] = *(const v8s*)&As[(wm * 64 + m * 16 + lr) * 64 + kk * 32 + lg * 8];
#pragma unroll
      for (int n = 0; n < 4; ++n)
        bb[n] = *(const v8s*)&Bs[(wn * 64 + n * 16 + lr) * 64 + kk * 32 + lg * 8];
#pragma unroll
      for (int m = 0; m < 4; ++m)
#pragma unroll
        for (int n = 0; n < 4; ++n)
          acc[m][n] = MFMA16(af[m], bb[n], acc[m][n]);
    }
    __syncthreads();
  }

  const bool relu = flags & 1, obf = flags & 2, qs = flags & 4;
#pragma unroll
  for (int n = 0; n < 4; ++n) {
    const int col = n0 + wn * 64 + n * 16 + lr;
    const float bv = bias ? bias[col] : 0.f;
#pragma unroll
    for (int m = 0; m < 4; ++m) {
      const int row = m0 + wm * 64 + m * 16 + lg * 4;
#pragma unroll
      for (int r = 0; r < 4; ++r) {
        float v = acc[m][n][r] + bv;
        if (qs) v *= QSCALE;
        if (relu) v = fmaxf(v, 0.f);
        if (obf) ((unsigned short*)C)[(size_t)(row + r) * N + col] = f2bf(v);
        else     ((float*)C)[(size_t)(row + r) * N + col] = v;
      }
    }
  }
}

// ---------------------------------------------------------------------------
// Flash attention: Q,K,V,O are [8192][1024] bf16, head slice = cols h*64..+63.
// Q pre-scaled by QSCALE (exp2-domain softmax). Block = 64 q rows (4 waves x
// 16), KV tiles of 64. All LDS tiles XOR-swizzled: elem col ^= (row&7)*8.
// C/D layout: row=(l>>4)*4+reg, col=l&15 (verified m89).
// ---------------------------------------------------------------------------
template <bool CAUSAL>
__global__ __launch_bounds__(256)
void flash_attn(const unsigned short* __restrict__ Q, const unsigned short* __restrict__ Kg,
                const unsigned short* __restrict__ Vg, unsigned short* __restrict__ O) {
  __shared__ __align__(16) unsigned short Kt[64 * 64];      // [kv][d], swizzled
  __shared__ __align__(16) unsigned short Vt[64 * 64];      // [d][kv], swizzled
  __shared__ __align__(16) unsigned short Pl[4 * 16 * 64];  // per-wave [16][64], swizzled
  const int tid = threadIdx.x;
  const int w = tid >> 6, l = tid & 63, lr = l & 15, lg = l >> 4;
  const int b = blockIdx.y >> 4, h = blockIdx.y & 15;
  const int q0 = blockIdx.x * 64 + w * 16;                  // batch-local q base of this wave
  const size_t base = ((size_t)b * 2048) * 1024 + h * 64;
  const int swz = (lr & 7) * 8;                             // fragment-read XOR (row&7)*8

  // Q fragments (A operand), held for the whole kv loop (already QSCALE'd)
  const unsigned short* qp = Q + base + (size_t)(q0 + lr) * 1024 + lg * 8;
  const v8s qf0 = *(const v8s*)qp;
  const v8s qf1 = *(const v8s*)(qp + 32);

  v4f acc[4];
  const v4f vzero = {0.f, 0.f, 0.f, 0.f};
#pragma unroll
  for (int n = 0; n < 4; ++n) acc[n] = vzero;
  float mrow[4] = {-INFINITY, -INFINITY, -INFINITY, -INFINITY};
  float lrow[4] = {0.f, 0.f, 0.f, 0.f};

  const int kv_end = CAUSAL ? (blockIdx.x * 64 + 64) : 2048;
  // K staging (pre-swizzled global source so linear gl_lds dest = swizzled LDS)
  const int kra = l >> 3, kka = ((l & 7) ^ (l >> 3)) * 8;
  // V staging: thread -> kv pair p (2 rows), d block d0 (8 cols)
  const int vp_ = tid & 31, vd0 = (tid >> 5) * 8;

  for (int kv0 = 0; kv0 < kv_end; kv0 += 64) {
#pragma unroll
    for (int i = 0; i < 2; ++i) {
      const int c = w + i * 4;
      gl_lds16(Kg + base + (size_t)(kv0 + c * 8 + kra) * 1024 + kka, &Kt[c * 512]);
    }
    // stage V transposed+swizzled: Vt[d][kv], packed u32 (kv pair) writes
    {
      const unsigned short* va = Vg + base + (size_t)(kv0 + 2 * vp_) * 1024 + vd0;
      const v8s v0 = *(const v8s*)va;
      const v8s v1 = *(const v8s*)(va + 1024);
#pragma unroll
      for (int j = 0; j < 8; ++j) {
        const unsigned int pk = (unsigned int)(unsigned short)v0[j] |
                                ((unsigned int)(unsigned short)v1[j] << 16);
        *(unsigned int*)&Vt[(vd0 + j) * 64 + ((2 * vp_) ^ (j * 8))] = pk;
      }
    }
    __syncthreads();

    // S = Q K^T (Q pre-scaled -> log2-domain scores)
    v4f s[4];
#pragma unroll
    for (int n = 0; n < 4; ++n) s[n] = vzero;
    __builtin_amdgcn_s_setprio(1);
#pragma unroll
    for (int kk = 0; kk < 2; ++kk) {
#pragma unroll
      for (int n = 0; n < 4; ++n) {
        const v8s kf = *(const v8s*)&Kt[(n * 16 + lr) * 64 + ((kk * 32 + lg * 8) ^ swz)];
        s[n] = MFMA16(kk ? qf1 : qf0, kf, s[n]);
      }
    }
    __builtin_amdgcn_s_setprio(0);

    if (CAUSAL && (kv0 + 63 > q0)) {
#pragma unroll
      for (int n = 0; n < 4; ++n) {
        const int kc = kv0 + n * 16 + lr;
#pragma unroll
        for (int r = 0; r < 4; ++r)
          if (kc > q0 + lg * 4 + r) s[n][r] = -INFINITY;
      }
    }

    // online softmax, exp2 domain (rows in regs: row = lg*4 + r; reduce over 16 lanes)
    float tm[4];
#pragma unroll
    for (int r = 0; r < 4; ++r)
      tm[r] = fmaxf(fmaxf(s[0][r], s[1][r]), fmaxf(s[2][r], s[3][r]));
#pragma unroll
    for (int off = 1; off < 16; off <<= 1)
#pragma unroll
      for (int r = 0; r < 4; ++r) tm[r] = fmaxf(tm[r], __shfl_xor(tm[r], off));

    // defer-max: only rescale when a row's max grew by more than 8 (T13)
    bool grow = false;
#pragma unroll
    for (int r = 0; r < 4; ++r) grow |= (tm[r] > mrow[r] + 8.f);
    if (__any(grow)) {
#pragma unroll
      for (int r = 0; r < 4; ++r) {
        const float mn = fmaxf(mrow[r], tm[r]);
        const float fac = fast_exp2(mrow[r] - mn);
        mrow[r] = mn;
        lrow[r] *= fac;
#pragma unroll
        for (int n = 0; n < 4; ++n) acc[n][r] *= fac;
      }
    }

    float rs[4];
#pragma unroll
    for (int n = 0; n < 4; ++n)
#pragma unroll
      for (int r = 0; r < 4; ++r) s[n][r] = fast_exp2(s[n][r] - mrow[r]);
#pragma unroll
    for (int r = 0; r < 4; ++r) rs[r] = (s[0][r] + s[1][r]) + (s[2][r] + s[3][r]);
#pragma unroll
    for (int off = 1; off < 16; off <<= 1)
#pragma unroll
      for (int r = 0; r < 4; ++r) rs[r] += __shfl_xor(rs[r], off);
#pragma unroll
    for (int r = 0; r < 4; ++r) lrow[r] += rs[r];

    // P -> per-wave LDS (C-frag -> A-frag re-layout), swizzled
    unsigned short* Pw = &Pl[w * 1024];
#pragma unroll
    for (int n = 0; n < 4; ++n)
#pragma unroll
      for (int r = 0; r < 4; ++r) {
        const int prow = lg * 4 + r;
        Pw[prow * 64 + ((n * 16 + lr) ^ ((prow & 7) * 8))] = f2bf(s[n][r]);
      }
    __builtin_amdgcn_s_setprio(1);
#pragma unroll
    for (int kk = 0; kk < 2; ++kk) {
      const v8s pf = *(const v8s*)&Pw[lr * 64 + ((kk * 32 + lg * 8) ^ swz)];
#pragma unroll
      for (int n = 0; n < 4; ++n) {
        const v8s vf = *(const v8s*)&Vt[(n * 16 + lr) * 64 + ((kk * 32 + lg * 8) ^ swz)];
        acc[n] = MFMA16(pf, vf, acc[n]);
      }
    }
    __builtin_amdgcn_s_setprio(0);
    __syncthreads();
  }

  // epilogue: O = acc / l
#pragma unroll
  for (int n = 0; n < 4; ++n)
#pragma unroll
    for (int r = 0; r < 4; ++r) {
      const float v = acc[n][r] / lrow[r];
      O[base + (size_t)(q0 + lg * 4 + r) * 1024 + n * 16 + lr] = f2bf(v);
    }
}

// ---------------------------------------------------------------------------
// Fused residual-add + LayerNorm (one block per token row of 1024)
// ---------------------------------------------------------------------------
__global__ __launch_bounds__(256)
void add_ln(const float* __restrict__ ra, const float* __restrict__ rb,
            const float* __restrict__ g, const float* __restrict__ be,
            float* __restrict__ of, unsigned short* __restrict__ act) {
  const int t = blockIdx.x, tid = threadIdx.x;
  const float4 va = ((const float4*)(ra + (size_t)t * 1024))[tid];
  const float4 vb = ((const float4*)(rb + (size_t)t * 1024))[tid];
  float4 s;
  s.x = va.x + vb.x; s.y = va.y + vb.y; s.z = va.z + vb.z; s.w = va.w + vb.w;
  float sum = s.x + s.y + s.z + s.w;
  float sq  = s.x * s.x + s.y * s.y + s.z * s.z + s.w * s.w;
#pragma unroll
  for (int off = 32; off > 0; off >>= 1) {
    sum += __shfl_xor(sum, off);
    sq  += __shfl_xor(sq, off);
  }
  __shared__ float red[8];
  const int w = tid >> 6;
  if ((tid & 63) == 0) { red[w] = sum; red[4 + w] = sq; }
  __syncthreads();
  sum = red[0] + red[1] + red[2] + red[3];
  sq  = red[4] + red[5] + red[6] + red[7];
  const float mean = sum * (1.f / 1024.f);
  const float var  = sq * (1.f / 1024.f) - mean * mean;
  const float rstd = rsqrtf(var + 1e-5f);
  const float4 gg = ((const float4*)g)[tid];
  const float4 bb = ((const float4*)be)[tid];
  float4 y;
  y.x = (s.x - mean) * rstd * gg.x + bb.x;
  y.y = (s.y - mean) * rstd * gg.y + bb.y;
  y.z = (s.z - mean) * rstd * gg.z + bb.z;
  y.w = (s.w - mean) * rstd * gg.w + bb.w;
  ((float4*)(of + (size_t)t * 1024))[tid] = y;
  if (act) {
    ushort4 u;
    u.x = f2bf(y.x); u.y = f2bf(y.y); u.z = f2bf(y.z); u.w = f2bf(y.w);
    ((ushort4*)(act + (size_t)t * 1024))[tid] = u;
  }
}

// ---------------------------------------------------------------------------
extern "C" void kernel_launch(void* const* d_in, const int* in_sizes, int n_in,
                              void* d_out, int out_size, void* d_ws, size_t ws_size,
                              hipStream_t stream) {
  const int*   x    = (const int*)d_in[0];
  const float* tok  = (const float*)d_in[1];
  const float* pos  = (const float*)d_in[2];
  const float* mWq  = (const float*)d_in[3];
  const float* mWk  = (const float*)d_in[4];
  const float* mWv  = (const float*)d_in[5];
  const float* mWo  = (const float*)d_in[6];
  const float* m_bo = (const float*)d_in[7];
  const float* hWq  = (const float*)d_in[8];
  const float* hWk  = (const float*)d_in[9];
  const float* hWv  = (const float*)d_in[10];
  const float* hWo  = (const float*)d_in[11];
  const float* h_bo = (const float*)d_in[12];
  const float* fW1  = (const float*)d_in[13];
  const float* f_b1 = (const float*)d_in[14];
  const float* fW2  = (const float*)d_in[15];
  const float* f_b2 = (const float*)d_in[16];
  const float* fW3  = (const float*)d_in[17];
  const float* f_b3 = (const float*)d_in[18];
  const float* fW4  = (const float*)d_in[19];
  const float* f_b4 = (const float*)d_in[20];
  const float* ln_g = (const float*)d_in[21];
  const float* ln_b = (const float*)d_in[22];

  char* ws = (char*)d_ws;
  const size_t MB = 1ull << 20;
  unsigned short* mWq_t = (unsigned short*)(ws + 0 * MB);
  unsigned short* mWk_t = (unsigned short*)(ws + 2 * MB);
  unsigned short* mWv_t = (unsigned short*)(ws + 4 * MB);
  unsigned short* mWo_t = (unsigned short*)(ws + 6 * MB);
  unsigned short* hWq_t = (unsigned short*)(ws + 8 * MB);
  unsigned short* hWk_t = (unsigned short*)(ws + 10 * MB);
  unsigned short* hWv_t = (unsigned short*)(ws + 12 * MB);
  unsigned short* hWo_t = (unsigned short*)(ws + 14 * MB);
  unsigned short* fW1_t = (unsigned short*)(ws + 16 * MB);
  unsigned short* fW2_t = (unsigned short*)(ws + 17 * MB);
  unsigned short* fW3_t = (unsigned short*)(ws + 18 * MB);
  unsigned short* fW4_t = (unsigned short*)(ws + 19 * MB);
  float*          resid = (float*)(ws + 20 * MB);           // 32 MB
  float*          tmp   = (float*)(ws + 52 * MB);           // 32 MB
  unsigned short* act   = (unsigned short*)(ws + 84 * MB);  // 16 MB
  unsigned short* qb    = (unsigned short*)(ws + 100 * MB); // 16 MB (also FFN h1)
  unsigned short* kb    = (unsigned short*)(ws + 116 * MB); // 16 MB (also FFN h2)
  unsigned short* vb    = (unsigned short*)(ws + 132 * MB); // 16 MB (also FFN h3)
  unsigned short* attno = (unsigned short*)(ws + 148 * MB); // 16 MB

  // ---- weight prep: f32 [K][N] -> bf16 [N][K]
  transpose_bf16<<<dim3(32, 32), 256, 0, stream>>>(mWq, mWq_t, 1024, 1024);
  transpose_bf16<<<dim3(32, 32), 256, 0, stream>>>(mWk, mWk_t, 1024, 1024);
  transpose_bf16<<<dim3(32, 32), 256, 0, stream>>>(mWv, mWv_t, 1024, 1024);
  transpose_bf16<<<dim3(32, 32), 256, 0, stream>>>(mWo, mWo_t, 1024, 1024);
  transpose_bf16<<<dim3(32, 32), 256, 0, stream>>>(hWq, hWq_t, 1024, 1024);
  transpose_bf16<<<dim3(32, 32), 256, 0, stream>>>(hWk, hWk_t, 1024, 1024);
  transpose_bf16<<<dim3(32, 32), 256, 0, stream>>>(hWv, hWv_t, 1024, 1024);
  transpose_bf16<<<dim3(32, 32), 256, 0, stream>>>(hWo, hWo_t, 1024, 1024);
  transpose_bf16<<<dim3(16, 32), 256, 0, stream>>>(fW1, fW1_t, 1024, 512);
  transpose_bf16<<<dim3(32, 16), 256, 0, stream>>>(fW2, fW2_t, 512, 1024);
  transpose_bf16<<<dim3(16, 32), 256, 0, stream>>>(fW3, fW3_t, 1024, 512);
  transpose_bf16<<<dim3(32, 16), 256, 0, stream>>>(fW4, fW4_t, 512, 1024);

  // ---- embedding
  embed_k<<<8192, 256, 0, stream>>>(x, tok, pos, resid, act);

  // ---- block 1: causal MHA (Q pre-scaled by QSCALE via flag bit2)
  gemm_bt<<<dim3(64, 8), 256, 0, stream>>>(act, mWq_t, nullptr, qb, 8192, 1024, 1024, 6);
  gemm_bt<<<dim3(64, 8), 256, 0, stream>>>(act, mWk_t, nullptr, kb, 8192, 1024, 1024, 2);
  gemm_bt<<<dim3(64, 8), 256, 0, stream>>>(act, mWv_t, nullptr, vb, 8192, 1024, 1024, 2);
  flash_attn<true><<<dim3(32, 64), 256, 0, stream>>>(qb, kb, vb, attno);
  gemm_bt<<<dim3(64, 8), 256, 0, stream>>>(attno, mWo_t, m_bo, tmp, 8192, 1024, 1024, 0);
  add_ln<<<8192, 256, 0, stream>>>(resid, tmp, ln_g, ln_b, resid, act);

  // ---- block 2: full (non-causal) MHA
  gemm_bt<<<dim3(64, 8), 256, 0, stream>>>(act, hWq_t, nullptr, qb, 8192, 1024, 1024, 6);
  gemm_bt<<<dim3(64, 8), 256, 0, stream>>>(act, hWk_t, nullptr, kb, 8192, 1024, 1024, 2);
  gemm_bt<<<dim3(64, 8), 256, 0, stream>>>(act, hWv_t, nullptr, vb, 8192, 1024, 1024, 2);
  flash_attn<false><<<dim3(32, 64), 256, 0, stream>>>(qb, kb, vb, attno);
  gemm_bt<<<dim3(64, 8), 256, 0, stream>>>(attno, hWo_t, h_bo, tmp, 8192, 1024, 1024, 0);
  add_ln<<<8192, 256, 0, stream>>>(resid, tmp, ln_g, ln_b, resid, act);

  // ---- FFN
  gemm_bt<<<dim3(64, 4), 256, 0, stream>>>(act, fW1_t, f_b1, qb, 8192, 512, 1024, 3);
  gemm_bt<<<dim3(64, 8), 256, 0, stream>>>(qb,  fW2_t, f_b2, kb, 8192, 1024, 512, 3);
  gemm_bt<<<dim3(64, 4), 256, 0, stream>>>(kb,  fW3_t, f_b3, vb, 8192, 512, 1024, 3);
  gemm_bt<<<dim3(64, 8), 256, 0, stream>>>(vb,  fW4_t, f_b4, tmp, 8192, 1024, 512, 0);
  add_ln<<<8192, 256, 0, stream>>>(resid, tmp, ln_g, ln_b, (float*)d_out, nullptr);
}

// Round 5
// 672.955 us; speedup vs baseline: 1.5854x; 1.2649x over previous
//
#include <hip/hip_runtime.h>
#include <hip/hip_bf16.h>

// ---------------------------------------------------------------------------
// Decoder block for B=4, T=2048, E=1024, H=16, HD=64, V=32000.
// bf16 MFMA compute, f32 residual/LN master copies.
// R3 (2nd resubmit after infra failures on dead container): flash_attn
// swapped-QK^T in-register softmax (T12): P never touches LDS, softmax
// reduce = 2 shuffles, cvt_pk P-pack; causal q-tile pairing (i, 31-i).
// ---------------------------------------------------------------------------

typedef __attribute__((ext_vector_type(8))) short v8s;   // 8 bf16 (4 VGPR) MFMA operand
typedef __attribute__((ext_vector_type(4))) short v4s;   // 4 bf16 (b64)
typedef __attribute__((ext_vector_type(4))) float v4f;   // MFMA accumulator
typedef __attribute__((ext_vector_type(4))) unsigned int v4u;

#define MFMA16(a, b, c) __builtin_amdgcn_mfma_f32_16x16x32_bf16((a), (b), (c), 0, 0, 0)

typedef const __attribute__((address_space(1))) void* gas1_t;
typedef __attribute__((address_space(3))) void* las3_t;

__device__ __forceinline__ void gl_lds16(const void* g, void* l) {
  // async global->LDS, 16B per lane; LDS dest must be wave-uniform (HW adds lane*16B)
  __builtin_amdgcn_global_load_lds((gas1_t)g, (las3_t)l, 16, 0, 0);
}

__device__ __forceinline__ unsigned short f2bf(float f) {
  __hip_bfloat16 h = __float2bfloat16(f);
  return *reinterpret_cast<unsigned short*>(&h);
}

__device__ __forceinline__ float fast_exp2(float x) {
  float r;
  asm("v_exp_f32 %0, %1" : "=v"(r) : "v"(x));  // D = 2^S0, -inf -> 0
  return r;
}

__device__ __forceinline__ unsigned int cvt_pk_bf16(float lo, float hi) {
  unsigned int r;
  asm("v_cvt_pk_bf16_f32 %0, %1, %2" : "=v"(r) : "v"(lo), "v"(hi));
  return r;
}

// log2(e)/sqrt(HD) folded into the Q projection
#define QSCALE 0.18033688011112042f

// ---------------------------------------------------------------------------
// Weight prep: src[K][N] f32 -> dst[N][K] bf16 (transpose + convert)
// ---------------------------------------------------------------------------
__global__ __launch_bounds__(256)
void transpose_bf16(const float* __restrict__ src, unsigned short* __restrict__ dst,
                    int K, int N) {
  __shared__ float tile[32][33];
  const int n0 = blockIdx.x * 32, k0 = blockIdx.y * 32;
  const int tx = threadIdx.x & 31, ty = threadIdx.x >> 5;  // 32 x 8
#pragma unroll
  for (int i = 0; i < 32; i += 8)
    tile[ty + i][tx] = src[(size_t)(k0 + ty + i) * N + n0 + tx];
  __syncthreads();
#pragma unroll
  for (int i = 0; i < 32; i += 8)
    dst[(size_t)(n0 + ty + i) * K + k0 + tx] = f2bf(tile[tx][ty + i]);
}

// ---------------------------------------------------------------------------
// Embedding: resid = tok_emb[x] + pos_emb, plus bf16 copy
// ---------------------------------------------------------------------------
__global__ __launch_bounds__(256)
void embed_k(const int* __restrict__ x, const float* __restrict__ tok,
             const float* __restrict__ pos, float* __restrict__ resid,
             unsigned short* __restrict__ act) {
  const int t = blockIdx.x, tid = threadIdx.x;
  const int id = x[t], tp = t & 2047;
  float4 v = ((const float4*)(tok + (size_t)id * 1024))[tid];
  float4 p = ((const float4*)(pos + (size_t)tp * 1024))[tid];
  v.x += p.x; v.y += p.y; v.z += p.z; v.w += p.w;
  ((float4*)(resid + (size_t)t * 1024))[tid] = v;
  ushort4 u;
  u.x = f2bf(v.x); u.y = f2bf(v.y); u.z = f2bf(v.z); u.w = f2bf(v.w);
  ((ushort4*)(act + (size_t)t * 1024))[tid] = u;
}

// ---------------------------------------------------------------------------
// GEMM: C[M][N] = A[M][K](bf16) @ Bt[N][K]^T(bf16)  (+bias) (+relu)
// flags: bit0 = relu, bit1 = bf16 output (else f32), bit2 = scale by QSCALE
// 128x128 tile, BK=64, 4 waves (2x2), each wave 64x64 via 4x4 16x16x32 MFMA.
// ---------------------------------------------------------------------------
__global__ __launch_bounds__(256)
void gemm_bt(const unsigned short* __restrict__ A, const unsigned short* __restrict__ Bt,
             const float* __restrict__ bias, void* __restrict__ C,
             int M, int N, int K, int flags) {
  __shared__ __align__(16) unsigned short As[128 * 64];
  __shared__ __align__(16) unsigned short Bs[128 * 64];
  const int tid = threadIdx.x;
  const int w = tid >> 6, l = tid & 63;
  const int lr = l & 15, lg = l >> 4;
  const int wm = w & 1, wn = w >> 1;
  const int m0 = blockIdx.x * 128, n0 = blockIdx.y * 128;
  const int ra = l >> 3, ka = (l & 7) * 8;   // staging: row-in-chunk, k offset

  v4f acc[4][4];
  const v4f vzero = {0.f, 0.f, 0.f, 0.f};
#pragma unroll
  for (int m = 0; m < 4; ++m)
#pragma unroll
    for (int n = 0; n < 4; ++n) acc[m][n] = vzero;

  for (int k0 = 0; k0 < K; k0 += 64) {
#pragma unroll
    for (int i = 0; i < 4; ++i) {
      const int c = w + i * 4;
      gl_lds16(A  + (size_t)(m0 + c * 8 + ra) * K + k0 + ka, &As[c * 512]);
      gl_lds16(Bt + (size_t)(n0 + c * 8 + ra) * K + k0 + ka, &Bs[c * 512]);
    }
    __syncthreads();
#pragma unroll
    for (int kk = 0; kk < 2; ++kk) {
      v8s af[4], bb[4];
#pragma unroll
      for (int m = 0; m < 4; ++m)
        af[m] = *(const v8s*)&As[(wm * 64 + m * 16 + lr) * 64 + kk * 32 + lg * 8];
#pragma unroll
      for (int n = 0; n < 4; ++n)
        bb[n] = *(const v8s*)&Bs[(wn * 64 + n * 16 + lr) * 64 + kk * 32 + lg * 8];
#pragma unroll
      for (int m = 0; m < 4; ++m)
#pragma unroll
        for (int n = 0; n < 4; ++n)
          acc[m][n] = MFMA16(af[m], bb[n], acc[m][n]);
    }
    __syncthreads();
  }

  const bool relu = flags & 1, obf = flags & 2, qs = flags & 4;
#pragma unroll
  for (int n = 0; n < 4; ++n) {
    const int col = n0 + wn * 64 + n * 16 + lr;
    const float bv = bias ? bias[col] : 0.f;
#pragma unroll
    for (int m = 0; m < 4; ++m) {
      const int row = m0 + wm * 64 + m * 16 + lg * 4;
#pragma unroll
      for (int r = 0; r < 4; ++r) {
        float v = acc[m][n][r] + bv;
        if (qs) v *= QSCALE;
        if (relu) v = fmaxf(v, 0.f);
        if (obf) ((unsigned short*)C)[(size_t)(row + r) * N + col] = f2bf(v);
        else     ((float*)C)[(size_t)(row + r) * N + col] = v;
      }
    }
  }
}

// ---------------------------------------------------------------------------
// Flash attention (swapped QK^T, in-register softmax):
// Q,K,V,O are [8192][1024] bf16, head slice = cols h*64..+63. Q pre-scaled
// by QSCALE (exp2 domain). Block = 64 q rows (4 waves x 16), KV tiles of 64.
// S^T = mfma(K, Q): lane holds kv = n*16+lg*4+r for its q = lane&15.
// P packs in-register (cvt_pk) as the PV A-frag with custom k-slot map
// (lg,j) -> kv = kk*32 + (j<4 ? lg*4+j : 16+lg*4+j-4); V B-frag reads use
// the identical map (2x ds_read_b64). LDS swizzles: Kt elem-col ^= (kv&7)*8,
// Vt[d][kv] elem-kv ^= (d&7)*8 (both conflict-free, R2-verified).
// CAUSAL: block handles q-tile pair (bx, 31-bx) -> 33 tile-iters per block.
// ---------------------------------------------------------------------------
template <bool CAUSAL>
__global__ __launch_bounds__(256)
void flash_attn(const unsigned short* __restrict__ Q, const unsigned short* __restrict__ Kg,
                const unsigned short* __restrict__ Vg, unsigned short* __restrict__ O) {
  __shared__ __align__(16) unsigned short Kt[64 * 64];      // [kv][d], swizzled
  __shared__ __align__(16) unsigned short Vt[64 * 64];      // [d][kv], swizzled
  const int tid = threadIdx.x;
  const int w = tid >> 6, l = tid & 63, lr = l & 15, lg = l >> 4;
  const int b = blockIdx.y >> 4, h = blockIdx.y & 15;
  const size_t base = ((size_t)b * 2048) * 1024 + h * 64;
  const int swz = (lr & 7) * 8;     // fragment-read XOR (elems)

  // K staging (pre-swizzled global source so linear gl_lds dest = swizzled LDS)
  const int kra = l >> 3, kka = ((l & 7) ^ (l >> 3)) * 8;
  // V staging: thread -> kv pair (2 rows), d block of 8
  const int vp_ = tid & 31, vd0 = (tid >> 5) * 8;

  const int nq = CAUSAL ? 2 : 1;
  for (int qi = 0; qi < nq; ++qi) {
    const int qt = CAUSAL ? (qi ? 31 - (int)blockIdx.x : (int)blockIdx.x)
                          : (int)blockIdx.x;
    const int q0w = qt * 64 + w * 16;                       // this wave's q base

    // Q fragments (B operand now), held for the whole kv loop (already QSCALE'd)
    const unsigned short* qp = Q + base + (size_t)(q0w + lr) * 1024 + lg * 8;
    const v8s qf0 = *(const v8s*)qp;
    const v8s qf1 = *(const v8s*)(qp + 32);

    v4f acc[4];
    const v4f vzero = {0.f, 0.f, 0.f, 0.f};
#pragma unroll
    for (int n = 0; n < 4; ++n) acc[n] = vzero;
    float mrow = -INFINITY, lrow = 0.f;                     // state for q = lr

    const int kv_end = CAUSAL ? qt * 64 + 64 : 2048;
    for (int kv0 = 0; kv0 < kv_end; kv0 += 64) {
#pragma unroll
      for (int i = 0; i < 2; ++i) {
        const int c = w + i * 4;
        gl_lds16(Kg + base + (size_t)(kv0 + c * 8 + kra) * 1024 + kka, &Kt[c * 512]);
      }
      // stage V transposed+swizzled: Vt[d][kv], packed u32 (kv pair) writes
      {
        const unsigned short* va = Vg + base + (size_t)(kv0 + 2 * vp_) * 1024 + vd0;
        const v8s v0 = *(const v8s*)va;
        const v8s v1 = *(const v8s*)(va + 1024);
#pragma unroll
        for (int j = 0; j < 8; ++j) {
          const unsigned int pk = (unsigned int)(unsigned short)v0[j] |
                                  ((unsigned int)(unsigned short)v1[j] << 16);
          *(unsigned int*)&Vt[(vd0 + j) * 64 + ((2 * vp_) ^ (j * 8))] = pk;
        }
      }
      __syncthreads();

      // S^T = mfma(K, Q): s[n][r] = S[kv = kv0+n*16+lg*4+r][q = q0w+lr]
      v4f s[4];
#pragma unroll
      for (int n = 0; n < 4; ++n) s[n] = vzero;
      __builtin_amdgcn_s_setprio(1);
#pragma unroll
      for (int kk = 0; kk < 2; ++kk) {
#pragma unroll
        for (int n = 0; n < 4; ++n) {
          const v8s kf = *(const v8s*)&Kt[(n * 16 + lr) * 64 + ((kk * 32 + lg * 8) ^ swz)];
          s[n] = MFMA16(kf, kk ? qf1 : qf0, s[n]);
        }
      }
      __builtin_amdgcn_s_setprio(0);

      if (CAUSAL && (kv0 + 63 > q0w)) {
        const int qg = q0w + lr;
#pragma unroll
        for (int n = 0; n < 4; ++n) {
          const int kvb = kv0 + n * 16 + lg * 4;
#pragma unroll
          for (int r = 0; r < 4; ++r)
            if (kvb + r > qg) s[n][r] = -INFINITY;
        }
      }

      // online softmax, exp2 domain; all 16 values of q=lr live in this lane
      float tm = fmaxf(fmaxf(fmaxf(s[0][0], s[0][1]), fmaxf(s[0][2], s[0][3])),
                       fmaxf(fmaxf(s[1][0], s[1][1]), fmaxf(s[1][2], s[1][3])));
      tm = fmaxf(tm, fmaxf(fmaxf(fmaxf(s[2][0], s[2][1]), fmaxf(s[2][2], s[2][3])),
                           fmaxf(fmaxf(s[3][0], s[3][1]), fmaxf(s[3][2], s[3][3]))));
      tm = fmaxf(tm, __shfl_xor(tm, 16));
      tm = fmaxf(tm, __shfl_xor(tm, 32));

      // defer-max (T13): rescale only when some row's max grew by > 8
      if (__any(tm > mrow + 8.f)) {
        const float mn = fmaxf(mrow, tm);
        const float fac = fast_exp2(mrow - mn);
        mrow = mn;
        lrow *= fac;
        // transpose fac to acc-row layout: acc row r holds q = lg*4 + r
        float facT[4];
#pragma unroll
        for (int r = 0; r < 4; ++r)
          facT[r] = __shfl(fac, (l & 48) | (lg * 4 + r));
#pragma unroll
        for (int n = 0; n < 4; ++n)
#pragma unroll
          for (int r = 0; r < 4; ++r) acc[n][r] *= facT[r];
      }

      float rs = 0.f;
#pragma unroll
      for (int n = 0; n < 4; ++n)
#pragma unroll
        for (int r = 0; r < 4; ++r) {
          s[n][r] = fast_exp2(s[n][r] - mrow);
          rs += s[n][r];
        }
      rs += __shfl_xor(rs, 16);
      rs += __shfl_xor(rs, 32);
      lrow += rs;

      // pack P in-register as PV A-frags (k-slot map: j<4 -> lg*4+j, else 16+lg*4+j-4)
      v4u pu0, pu1;
      pu0.x = cvt_pk_bf16(s[0][0], s[0][1]); pu0.y = cvt_pk_bf16(s[0][2], s[0][3]);
      pu0.z = cvt_pk_bf16(s[1][0], s[1][1]); pu0.w = cvt_pk_bf16(s[1][2], s[1][3]);
      pu1.x = cvt_pk_bf16(s[2][0], s[2][1]); pu1.y = cvt_pk_bf16(s[2][2], s[2][3]);
      pu1.z = cvt_pk_bf16(s[3][0], s[3][1]); pu1.w = cvt_pk_bf16(s[3][2], s[3][3]);
      v8s pf0, pf1;
      __builtin_memcpy(&pf0, &pu0, 16);
      __builtin_memcpy(&pf1, &pu1, 16);

      // PV: B-frag of V with the same k-slot map; 2x ds_read_b64 per (n,kk)
      __builtin_amdgcn_s_setprio(1);
#pragma unroll
      for (int kk = 0; kk < 2; ++kk) {
#pragma unroll
        for (int n = 0; n < 4; ++n) {
          const int rowb = (n * 16 + lr) * 64;
          const v4s va_ = *(const v4s*)&Vt[rowb + ((kk * 32 + lg * 4) ^ swz)];
          const v4s vb_ = *(const v4s*)&Vt[rowb + ((kk * 32 + 16 + lg * 4) ^ swz)];
          const v8s vf = __builtin_shufflevector(va_, vb_, 0, 1, 2, 3, 4, 5, 6, 7);
          acc[n] = MFMA16(kk ? pf1 : pf0, vf, acc[n]);
        }
      }
      __builtin_amdgcn_s_setprio(0);
      __syncthreads();
    }

    // epilogue: O = acc / l (l lives at q=lr; acc row r is q=lg*4+r -> transpose)
    float lT[4];
#pragma unroll
    for (int r = 0; r < 4; ++r)
      lT[r] = __shfl(lrow, (l & 48) | (lg * 4 + r));
#pragma unroll
    for (int n = 0; n < 4; ++n)
#pragma unroll
      for (int r = 0; r < 4; ++r) {
        const float v = acc[n][r] / lT[r];
        O[base + (size_t)(q0w + lg * 4 + r) * 1024 + n * 16 + lr] = f2bf(v);
      }
  }
}

// ---------------------------------------------------------------------------
// Fused residual-add + LayerNorm (one block per token row of 1024)
// ---------------------------------------------------------------------------
__global__ __launch_bounds__(256)
void add_ln(const float* __restrict__ ra, const float* __restrict__ rb,
            const float* __restrict__ g, const float* __restrict__ be,
            float* __restrict__ of, unsigned short* __restrict__ act) {
  const int t = blockIdx.x, tid = threadIdx.x;
  const float4 va = ((const float4*)(ra + (size_t)t * 1024))[tid];
  const float4 vb = ((const float4*)(rb + (size_t)t * 1024))[tid];
  float4 s;
  s.x = va.x + vb.x; s.y = va.y + vb.y; s.z = va.z + vb.z; s.w = va.w + vb.w;
  float sum = s.x + s.y + s.z + s.w;
  float sq  = s.x * s.x + s.y * s.y + s.z * s.z + s.w * s.w;
#pragma unroll
  for (int off = 32; off > 0; off >>= 1) {
    sum += __shfl_xor(sum, off);
    sq  += __shfl_xor(sq, off);
  }
  __shared__ float red[8];
  const int w = tid >> 6;
  if ((tid & 63) == 0) { red[w] = sum; red[4 + w] = sq; }
  __syncthreads();
  sum = red[0] + red[1] + red[2] + red[3];
  sq  = red[4] + red[5] + red[6] + red[7];
  const float mean = sum * (1.f / 1024.f);
  const float var  = sq * (1.f / 1024.f) - mean * mean;
  const float rstd = rsqrtf(var + 1e-5f);
  const float4 gg = ((const float4*)g)[tid];
  const float4 bb = ((const float4*)be)[tid];
  float4 y;
  y.x = (s.x - mean) * rstd * gg.x + bb.x;
  y.y = (s.y - mean) * rstd * gg.y + bb.y;
  y.z = (s.z - mean) * rstd * gg.z + bb.z;
  y.w = (s.w - mean) * rstd * gg.w + bb.w;
  ((float4*)(of + (size_t)t * 1024))[tid] = y;
  if (act) {
    ushort4 u;
    u.x = f2bf(y.x); u.y = f2bf(y.y); u.z = f2bf(y.z); u.w = f2bf(y.w);
    ((ushort4*)(act + (size_t)t * 1024))[tid] = u;
  }
}

// ---------------------------------------------------------------------------
extern "C" void kernel_launch(void* const* d_in, const int* in_sizes, int n_in,
                              void* d_out, int out_size, void* d_ws, size_t ws_size,
                              hipStream_t stream) {
  const int*   x    = (const int*)d_in[0];
  const float* tok  = (const float*)d_in[1];
  const float* pos  = (const float*)d_in[2];
  const float* mWq  = (const float*)d_in[3];
  const float* mWk  = (const float*)d_in[4];
  const float* mWv  = (const float*)d_in[5];
  const float* mWo  = (const float*)d_in[6];
  const float* m_bo = (const float*)d_in[7];
  const float* hWq  = (const float*)d_in[8];
  const float* hWk  = (const float*)d_in[9];
  const float* hWv  = (const float*)d_in[10];
  const float* hWo  = (const float*)d_in[11];
  const float* h_bo = (const float*)d_in[12];
  const float* fW1  = (const float*)d_in[13];
  const float* f_b1 = (const float*)d_in[14];
  const float* fW2  = (const float*)d_in[15];
  const float* f_b2 = (const float*)d_in[16];
  const float* fW3  = (const float*)d_in[17];
  const float* f_b3 = (const float*)d_in[18];
  const float* fW4  = (const float*)d_in[19];
  const float* f_b4 = (const float*)d_in[20];
  const float* ln_g = (const float*)d_in[21];
  const float* ln_b = (const float*)d_in[22];

  char* ws = (char*)d_ws;
  const size_t MB = 1ull << 20;
  unsigned short* mWq_t = (unsigned short*)(ws + 0 * MB);
  unsigned short* mWk_t = (unsigned short*)(ws + 2 * MB);
  unsigned short* mWv_t = (unsigned short*)(ws + 4 * MB);
  unsigned short* mWo_t = (unsigned short*)(ws + 6 * MB);
  unsigned short* hWq_t = (unsigned short*)(ws + 8 * MB);
  unsigned short* hWk_t = (unsigned short*)(ws + 10 * MB);
  unsigned short* hWv_t = (unsigned short*)(ws + 12 * MB);
  unsigned short* hWo_t = (unsigned short*)(ws + 14 * MB);
  unsigned short* fW1_t = (unsigned short*)(ws + 16 * MB);
  unsigned short* fW2_t = (unsigned short*)(ws + 17 * MB);
  unsigned short* fW3_t = (unsigned short*)(ws + 18 * MB);
  unsigned short* fW4_t = (unsigned short*)(ws + 19 * MB);
  float*          resid = (float*)(ws + 20 * MB);           // 32 MB
  float*          tmp   = (float*)(ws + 52 * MB);           // 32 MB
  unsigned short* act   = (unsigned short*)(ws + 84 * MB);  // 16 MB
  unsigned short* qb    = (unsigned short*)(ws + 100 * MB); // 16 MB (also FFN h1)
  unsigned short* kb    = (unsigned short*)(ws + 116 * MB); // 16 MB (also FFN h2)
  unsigned short* vb    = (unsigned short*)(ws + 132 * MB); // 16 MB (also FFN h3)
  unsigned short* attno = (unsigned short*)(ws + 148 * MB); // 16 MB

  // ---- weight prep: f32 [K][N] -> bf16 [N][K]
  transpose_bf16<<<dim3(32, 32), 256, 0, stream>>>(mWq, mWq_t, 1024, 1024);
  transpose_bf16<<<dim3(32, 32), 256, 0, stream>>>(mWk, mWk_t, 1024, 1024);
  transpose_bf16<<<dim3(32, 32), 256, 0, stream>>>(mWv, mWv_t, 1024, 1024);
  transpose_bf16<<<dim3(32, 32), 256, 0, stream>>>(mWo, mWo_t, 1024, 1024);
  transpose_bf16<<<dim3(32, 32), 256, 0, stream>>>(hWq, hWq_t, 1024, 1024);
  transpose_bf16<<<dim3(32, 32), 256, 0, stream>>>(hWk, hWk_t, 1024, 1024);
  transpose_bf16<<<dim3(32, 32), 256, 0, stream>>>(hWv, hWv_t, 1024, 1024);
  transpose_bf16<<<dim3(32, 32), 256, 0, stream>>>(hWo, hWo_t, 1024, 1024);
  transpose_bf16<<<dim3(16, 32), 256, 0, stream>>>(fW1, fW1_t, 1024, 512);
  transpose_bf16<<<dim3(32, 16), 256, 0, stream>>>(fW2, fW2_t, 512, 1024);
  transpose_bf16<<<dim3(16, 32), 256, 0, stream>>>(fW3, fW3_t, 1024, 512);
  transpose_bf16<<<dim3(32, 16), 256, 0, stream>>>(fW4, fW4_t, 512, 1024);

  // ---- embedding
  embed_k<<<8192, 256, 0, stream>>>(x, tok, pos, resid, act);

  // ---- block 1: causal MHA (Q pre-scaled by QSCALE via flag bit2)
  gemm_bt<<<dim3(64, 8), 256, 0, stream>>>(act, mWq_t, nullptr, qb, 8192, 1024, 1024, 6);
  gemm_bt<<<dim3(64, 8), 256, 0, stream>>>(act, mWk_t, nullptr, kb, 8192, 1024, 1024, 2);
  gemm_bt<<<dim3(64, 8), 256, 0, stream>>>(act, mWv_t, nullptr, vb, 8192, 1024, 1024, 2);
  flash_attn<true><<<dim3(16, 64), 256, 0, stream>>>(qb, kb, vb, attno);
  gemm_bt<<<dim3(64, 8), 256, 0, stream>>>(attno, mWo_t, m_bo, tmp, 8192, 1024, 1024, 0);
  add_ln<<<8192, 256, 0, stream>>>(resid, tmp, ln_g, ln_b, resid, act);

  // ---- block 2: full (non-causal) MHA
  gemm_bt<<<dim3(64, 8), 256, 0, stream>>>(act, hWq_t, nullptr, qb, 8192, 1024, 1024, 6);
  gemm_bt<<<dim3(64, 8), 256, 0, stream>>>(act, hWk_t, nullptr, kb, 8192, 1024, 1024, 2);
  gemm_bt<<<dim3(64, 8), 256, 0, stream>>>(act, hWv_t, nullptr, vb, 8192, 1024, 1024, 2);
  flash_attn<false><<<dim3(32, 64), 256, 0, stream>>>(qb, kb, vb, attno);
  gemm_bt<<<dim3(64, 8), 256, 0, stream>>>(attno, hWo_t, h_bo, tmp, 8192, 1024, 1024, 0);
  add_ln<<<8192, 256, 0, stream>>>(resid, tmp, ln_g, ln_b, resid, act);

  // ---- FFN
  gemm_bt<<<dim3(64, 4), 256, 0, stream>>>(act, fW1_t, f_b1, qb, 8192, 512, 1024, 3);
  gemm_bt<<<dim3(64, 8), 256, 0, stream>>>(qb,  fW2_t, f_b2, kb, 8192, 1024, 512, 3);
  gemm_bt<<<dim3(64, 4), 256, 0, stream>>>(kb,  fW3_t, f_b3, vb, 8192, 512, 1024, 3);
  gemm_bt<<<dim3(64, 8), 256, 0, stream>>>(vb,  fW4_t, f_b4, tmp, 8192, 1024, 512, 0);
  add_ln<<<8192, 256, 0, stream>>>(resid, tmp, ln_g, ln_b, (float*)d_out, nullptr);
}